// Round 4
// baseline (400.231 us; speedup 1.0000x reference)
//
#include <hip/hip_runtime.h>
#include <math.h>

#define D 1024
#define L 2048
#define B 32

typedef float v4f __attribute__((ext_vector_type(4)));

// Kernel 1: u[b][d] = sum_e hidden[b][e] * W[e][d]
// Block owns (b, 64-column chunk of d); reduction over all e done in-block:
// wave w handles e = w, w+4, ... (256 e each), LDS combine at the end.
// No atomics, no pre-zeroing. Grid = 32*16 = 512 blocks (2/CU).
__global__ void compute_u(const float* __restrict__ hidden,
                          const float* __restrict__ W,
                          float* __restrict__ u) {
    __shared__ float h[D];
    __shared__ float part[4][64];
    const int b     = blockIdx.x >> 4;   // 0..31
    const int chunk = blockIdx.x & 15;   // 0..15
    const int t = threadIdx.x;           // 0..255
    const int lane = t & 63, wv = t >> 6;
    ((float4*)h)[t] = ((const float4*)(hidden + (size_t)b * D))[t];
    __syncthreads();
    const int d = chunk * 64 + lane;
    float acc = 0.f;
#pragma unroll 8
    for (int e = wv; e < D; e += 4) {
        acc += h[e] * W[(size_t)e * D + d];  // 64-lane coalesced 256B row segment
    }
    part[wv][lane] = acc;
    __syncthreads();
    if (t < 64) {
        u[(size_t)b * D + chunk * 64 + t] =
            part[0][t] + part[1][t] + part[2][t] + part[3][t];
    }
}

// Kernel 2: scores[b][l] = enc[l,b,:] . u[b,:]
// One wave handles 8 consecutive l for ONE b. 8192 waves = 2048 blocks.
// Plain loads: enc was just d2d-restored by the harness, so much of it is
// L3-resident — let the cache serve it.
__global__ void compute_scores(const float* __restrict__ enc,
                               const float* __restrict__ u,
                               float* __restrict__ scores) {
    const int wave = threadIdx.x >> 6;          // 0..3
    const int lane = threadIdx.x & 63;
    const int q = blockIdx.x * 4 + wave;        // 0..8191
    const int b = q & (B - 1);
    const int lbase = (q >> 5) * 8;             // 0,8,...,2040
    const v4f* u4 = (const v4f*)(u + (size_t)b * D);
    v4f uv[4];
#pragma unroll
    for (int i = 0; i < 4; ++i) uv[i] = u4[i * 64 + lane];
    float acc[8];
#pragma unroll
    for (int j = 0; j < 8; ++j) {
        const v4f* e4 = (const v4f*)(enc + ((size_t)(lbase + j) * B + b) * D);
        float a = 0.f;
#pragma unroll
        for (int i = 0; i < 4; ++i) {
            v4f ev = e4[i * 64 + lane];
            a += ev.x * uv[i].x + ev.y * uv[i].y + ev.z * uv[i].z + ev.w * uv[i].w;
        }
        acc[j] = a;
    }
#pragma unroll
    for (int j = 0; j < 8; ++j)
#pragma unroll
        for (int off = 32; off >= 1; off >>= 1) acc[j] += __shfl_xor(acc[j], off, 64);
    if (lane == 0) {
        float* sp = scores + (size_t)b * L + lbase;
        float4 o0 = {acc[0], acc[1], acc[2], acc[3]};
        float4 o1 = {acc[4], acc[5], acc[6], acc[7]};
        *(float4*)(sp + 0) = o0;
        *(float4*)(sp + 4) = o1;
    }
}

// Kernel 3: out[b,:] = softmax(scores[b,:]) over L=2048. One block per b, 1024 thr.
__global__ void softmax_rows(const float* __restrict__ scores,
                             float* __restrict__ out) {
    const int b = blockIdx.x;
    const int t = threadIdx.x;             // 0..1023
    const int lane = t & 63, wv = t >> 6;  // 16 waves
    const float* row = scores + (size_t)b * L;
    float v0 = row[t];
    float v1 = row[t + 1024];
    float m = fmaxf(v0, v1);
#pragma unroll
    for (int off = 32; off >= 1; off >>= 1) m = fmaxf(m, __shfl_xor(m, off, 64));
    __shared__ float redm[16];
    __shared__ float reds[16];
    if (lane == 0) redm[wv] = m;
    __syncthreads();
    m = redm[0];
#pragma unroll
    for (int k = 1; k < 16; ++k) m = fmaxf(m, redm[k]);
    v0 = __expf(v0 - m);
    v1 = __expf(v1 - m);
    float s = v0 + v1;
#pragma unroll
    for (int off = 32; off >= 1; off >>= 1) s += __shfl_xor(s, off, 64);
    if (lane == 0) reds[wv] = s;
    __syncthreads();
    s = reds[0];
#pragma unroll
    for (int k = 1; k < 16; ++k) s += reds[k];
    const float inv = 1.f / s;
    out[(size_t)b * L + t] = v0 * inv;
    out[(size_t)b * L + t + 1024] = v1 * inv;
}

extern "C" void kernel_launch(void* const* d_in, const int* in_sizes, int n_in,
                              void* d_out, int out_size, void* d_ws, size_t ws_size,
                              hipStream_t stream) {
    const float* hidden = (const float*)d_in[0];  // [B, D]
    const float* enc    = (const float*)d_in[1];  // [L, B, D]
    const float* W      = (const float*)d_in[2];  // [D, D]
    // d_in[3] (bias) cancels in the softmax: hidden.b is constant along l.
    float* u      = (float*)d_ws;        // [B, D]  = 128 KB (fully written by compute_u)
    float* scores = u + (size_t)B * D;   // [B, L]  = 256 KB (fully written)
    float* out    = (float*)d_out;       // [B, L]

    compute_u<<<B * 16, 256, 0, stream>>>(hidden, W, u);
    compute_scores<<<(L * B) / 32, 256, 0, stream>>>(enc, u, scores);
    softmax_rows<<<B, 1024, 0, stream>>>(scores, out);
}

// Round 5
// 369.335 us; speedup vs baseline: 1.0837x; 1.0837x over previous
//
#include <hip/hip_runtime.h>
#include <math.h>

#define D 1024
#define L 2048
#define B 32

typedef float v4f __attribute__((ext_vector_type(4)));

// Kernel 1: u[b][d] = sum_e hidden[b][e] * W[e][d]
// Block owns (b, 64-column chunk of d); reduction over all e done in-block:
// wave w handles e = w, w+4, ... (256 e each), LDS combine at the end.
// No atomics, no pre-zeroing. Grid = 32*16 = 512 blocks (2/CU).
__global__ void compute_u(const float* __restrict__ hidden,
                          const float* __restrict__ W,
                          float* __restrict__ u) {
    __shared__ float h[D];
    __shared__ float part[4][64];
    const int b     = blockIdx.x >> 4;   // 0..31
    const int chunk = blockIdx.x & 15;   // 0..15
    const int t = threadIdx.x;           // 0..255
    const int lane = t & 63, wv = t >> 6;
    ((float4*)h)[t] = ((const float4*)(hidden + (size_t)b * D))[t];
    __syncthreads();
    const int d = chunk * 64 + lane;
    float acc = 0.f;
#pragma unroll 8
    for (int e = wv; e < D; e += 4) {
        acc += h[e] * W[(size_t)e * D + d];  // 64-lane coalesced 256B row segment
    }
    part[wv][lane] = acc;
    __syncthreads();
    if (t < 64) {
        u[(size_t)b * D + chunk * 64 + t] =
            part[0][t] + part[1][t] + part[2][t] + part[3][t];
    }
}

// Kernel 2: scores[b][l] = enc[l,b,:] . u[b,:]
// One wave handles 8 consecutive l for ONE b. 8192 waves = 2048 blocks.
// enc loads are NONTEMPORAL: enc is a 256 MiB one-shot stream, always
// HBM-cold (the 1 GB ws poison flushes L3 before we run); nt keeps the
// stream from churning L2 (full of dirty poison lines) — R4 showed
// removing nt cost ~+30 us.
__global__ void compute_scores(const float* __restrict__ enc,
                               const float* __restrict__ u,
                               float* __restrict__ scores) {
    const int wave = threadIdx.x >> 6;          // 0..3
    const int lane = threadIdx.x & 63;
    const int q = blockIdx.x * 4 + wave;        // 0..8191
    const int b = q & (B - 1);
    const int lbase = (q >> 5) * 8;             // 0,8,...,2040
    const v4f* u4 = (const v4f*)(u + (size_t)b * D);
    v4f uv[4];
#pragma unroll
    for (int i = 0; i < 4; ++i) uv[i] = u4[i * 64 + lane];
    float acc[8];
#pragma unroll
    for (int j = 0; j < 8; ++j) {
        const v4f* e4 = (const v4f*)(enc + ((size_t)(lbase + j) * B + b) * D);
        float a = 0.f;
#pragma unroll
        for (int i = 0; i < 4; ++i) {
            v4f ev = __builtin_nontemporal_load(e4 + i * 64 + lane);
            a += ev.x * uv[i].x + ev.y * uv[i].y + ev.z * uv[i].z + ev.w * uv[i].w;
        }
        acc[j] = a;
    }
#pragma unroll
    for (int j = 0; j < 8; ++j)
#pragma unroll
        for (int off = 32; off >= 1; off >>= 1) acc[j] += __shfl_xor(acc[j], off, 64);
    if (lane == 0) {
        float* sp = scores + (size_t)b * L + lbase;
        float4 o0 = {acc[0], acc[1], acc[2], acc[3]};
        float4 o1 = {acc[4], acc[5], acc[6], acc[7]};
        *(float4*)(sp + 0) = o0;
        *(float4*)(sp + 4) = o1;
    }
}

// Kernel 3: out[b,:] = softmax(scores[b,:]) over L=2048. One block per b, 1024 thr.
__global__ void softmax_rows(const float* __restrict__ scores,
                             float* __restrict__ out) {
    const int b = blockIdx.x;
    const int t = threadIdx.x;             // 0..1023
    const int lane = t & 63, wv = t >> 6;  // 16 waves
    const float* row = scores + (size_t)b * L;
    float v0 = row[t];
    float v1 = row[t + 1024];
    float m = fmaxf(v0, v1);
#pragma unroll
    for (int off = 32; off >= 1; off >>= 1) m = fmaxf(m, __shfl_xor(m, off, 64));
    __shared__ float redm[16];
    __shared__ float reds[16];
    if (lane == 0) redm[wv] = m;
    __syncthreads();
    m = redm[0];
#pragma unroll
    for (int k = 1; k < 16; ++k) m = fmaxf(m, redm[k]);
    v0 = __expf(v0 - m);
    v1 = __expf(v1 - m);
    float s = v0 + v1;
#pragma unroll
    for (int off = 32; off >= 1; off >>= 1) s += __shfl_xor(s, off, 64);
    if (lane == 0) reds[wv] = s;
    __syncthreads();
    s = reds[0];
#pragma unroll
    for (int k = 1; k < 16; ++k) s += reds[k];
    const float inv = 1.f / s;
    out[(size_t)b * L + t] = v0 * inv;
    out[(size_t)b * L + t + 1024] = v1 * inv;
}

extern "C" void kernel_launch(void* const* d_in, const int* in_sizes, int n_in,
                              void* d_out, int out_size, void* d_ws, size_t ws_size,
                              hipStream_t stream) {
    const float* hidden = (const float*)d_in[0];  // [B, D]
    const float* enc    = (const float*)d_in[1];  // [L, B, D]
    const float* W      = (const float*)d_in[2];  // [D, D]
    // d_in[3] (bias) cancels in the softmax: hidden.b is constant along l.
    float* u      = (float*)d_ws;        // [B, D]  = 128 KB (fully written by compute_u)
    float* scores = u + (size_t)B * D;   // [B, L]  = 256 KB (fully written)
    float* out    = (float*)d_out;       // [B, L]

    compute_u<<<B * 16, 256, 0, stream>>>(hidden, W, u);
    compute_scores<<<(L * B) / 32, 256, 0, stream>>>(enc, u, scores);
    softmax_rows<<<B, 1024, 0, stream>>>(scores, out);
}